// Round 1
// baseline (4584.042 us; speedup 1.0000x reference)
//
#include <hip/hip_runtime.h>
#include <hip/hip_cooperative_groups.h>

namespace cg = cooperative_groups;

typedef unsigned int u32;
typedef unsigned long long u64;
typedef unsigned char u8;

static constexpr int SORTN = 131072;   // pow2 >= max chosen count (<= N = 100000)
static constexpr int STILE = 2048;     // bitonic LDS tile (16 KiB of u64)
static constexpr int MAXR  = 192;      // matching round cap (expect ~20-30)
static constexpr int MBLK  = 256;      // match kernel blocks (cooperative, 1/CU)

// monotonic float->uint mapping (ascending)
__device__ __forceinline__ u32 ordf(float f) {
  u32 u = __float_as_uint(f);
  return (u & 0x80000000u) ? ~u : (u | 0x80000000u);
}
__device__ __forceinline__ float inv_ordf(u32 m) {
  return __uint_as_float((m & 0x80000000u) ? (m ^ 0x80000000u) : ~m);
}

__global__ __launch_bounds__(256)
void k_init(u32* m_ord, double* ssum, u8* matched, u64* node_min,
            float* scoreC, u64* sortbuf, u32* flags, u32* scalars, int N) {
  int i = blockIdx.x * blockDim.x + threadIdx.x;
  if (i < N) {
    m_ord[i] = 0u; ssum[i] = 0.0; matched[i] = 0;
    node_min[i] = ~0ull; node_min[(size_t)N + i] = ~0ull;
    scoreC[i] = 1.0f;   // singleton clusters keep score 1.0
  }
  if (i < SORTN) sortbuf[i] = ~0ull;  // padding sorts to the end
  if (i < 256)   flags[i] = 0u;
  if (i < 16)    scalars[i] = 0u;
}

// wave-per-node dual dot product: s_src = x.W[:256], s_dst = x.W[256:]
__global__ __launch_bounds__(256)
void k_dots(const float4* __restrict__ x4, const float4* __restrict__ W4,
            float* __restrict__ s_src, float* __restrict__ s_dst, int N) {
  int gt = blockIdx.x * blockDim.x + threadIdx.x;
  int w = gt >> 6, lane = gt & 63;
  if (w >= N) return;
  float4 xa = x4[(size_t)w * 64 + lane];
  float4 wa = W4[lane];
  float4 wb = W4[64 + lane];
  float pa = xa.x*wa.x + xa.y*wa.y + xa.z*wa.z + xa.w*wa.w;
  float pb = xa.x*wb.x + xa.y*wb.y + xa.z*wb.z + xa.w*wb.w;
  #pragma unroll
  for (int m = 32; m >= 1; m >>= 1) {
    pa += __shfl_xor(pa, m);
    pb += __shfl_xor(pb, m);
  }
  if (lane == 0) { s_src[w] = pa; s_dst[w] = pb; }
}

// segment max over dst (exact, via ordered-uint atomicMax)
__global__ __launch_bounds__(256)
void k_max(const int* __restrict__ src, const int* __restrict__ dst,
           const float* __restrict__ s_src, const float* __restrict__ s_dst,
           const float* __restrict__ bvec, u32* m_ord, int E) {
  int e = blockIdx.x * blockDim.x + threadIdx.x;
  if (e >= E) return;
  int d = dst[e];
  float r = s_src[src[e]] + s_dst[d] + bvec[0];
  atomicMax(&m_ord[d], ordf(r));
}

// exp(raw - max), f64 segment-sum (deterministic to f32 rounding)
__global__ __launch_bounds__(256)
void k_expsum(const int* __restrict__ src, const int* __restrict__ dst,
              const float* __restrict__ s_src, const float* __restrict__ s_dst,
              const float* __restrict__ bvec, const u32* __restrict__ m_ord,
              float* __restrict__ exb, double* ssum, int E) {
  int e = blockIdx.x * blockDim.x + threadIdx.x;
  if (e >= E) return;
  int d = dst[e];
  float r = s_src[src[e]] + s_dst[d] + bvec[0];
  float m = inv_ordf(m_ord[d]);
  float ex = expf(r - m);
  exb[e] = ex;
  atomicAdd(&ssum[d], (double)ex);
}

// score = softmax + 0.5; key = (~ord(score))<<32 | edge_id  (asc key == desc score, index tiebreak)
__global__ __launch_bounds__(256)
void k_scorekey(const int* __restrict__ dst, const float* __restrict__ exb,
                const double* __restrict__ ssum, float* __restrict__ esc,
                u64* __restrict__ key, u8* __restrict__ alive, int E) {
  int e = blockIdx.x * blockDim.x + threadIdx.x;
  if (e >= E) return;
  float s = (float)ssum[dst[e]];
  float p = exb[e] / s;
  float es = p + 0.5f;
  esc[e] = es;
  key[e] = ((u64)(~ordf(es)) << 32) | (u32)e;
  alive[e] = 1;
}

// locally-dominant matching, cooperative, 2 grid-syncs per round.
// alive(e) == !matched[src] && !matched[dst]; alive[] is a lazily-updated cache.
__global__ __launch_bounds__(256)
void k_match(const int* __restrict__ src, const int* __restrict__ dst,
             const u64* __restrict__ key, u8* alive, u8* matched,
             u64* node_min, u64* sortbuf, u32* flags, u32* scalars,
             int N, int E) {
  cg::grid_group g = cg::this_grid();
  __shared__ u32 sflag;
  const int tid = blockIdx.x * blockDim.x + threadIdx.x;
  const int nth = gridDim.x * blockDim.x;
  int cur = 0;
  for (int r = 0; r < MAXR; ++r) {
    u64* nm  = node_min + (size_t)cur * N;
    u64* nmn = node_min + (size_t)(cur ^ 1) * N;
    bool any = false;
    for (int e = tid; e < E; e += nth) {
      if (!alive[e]) continue;
      int s = src[e], d = dst[e];
      if (matched[s] | matched[d]) { alive[e] = 0; continue; }
      any = true;
      u64 k = key[e];
      atomicMin(&nm[s], k);
      if (d != s) atomicMin(&nm[d], k);
    }
    for (int v = tid; v < N; v += nth) nmn[v] = ~0ull;  // reset next-round buffer
    u64 bal = __ballot(any);
    if (bal != 0ull && (threadIdx.x & 63) == 0) atomicOr(&flags[r], 1u);
    __threadfence();
    g.sync();
    __threadfence();
    if (threadIdx.x == 0) sflag = atomicOr(&flags[r], 0u);
    __syncthreads();
    u32 f = sflag;
    __syncthreads();
    if (f == 0) break;   // no alive edges -> done (grid-uniform)
    // pick: edge is min at BOTH endpoints (keys unique -> vertex-disjoint picks)
    for (int e = tid; e < E; e += nth) {
      if (!alive[e]) continue;
      int s = src[e], d = dst[e];
      u64 k = key[e];
      if (nm[s] == k && nm[d] == k) {
        matched[s] = 1; matched[d] = 1;
        alive[e] = 0;
        u32 i = atomicAdd(&scalars[0], 1u);   // compaction (order fixed by later sort)
        sortbuf[i] = k;
      }
    }
    __threadfence();
    g.sync();
    __threadfence();
    cur ^= 1;
  }
}

// bitonic sort of SORTN u64 keys, cooperative (64 blocks), LDS tiles of 2048
__global__ __launch_bounds__(256)
void k_sort(u64* buf) {
  cg::grid_group g = cg::this_grid();
  __shared__ u64 t[STILE];
  const int b = blockIdx.x;
  const int base = b * STILE;
  const int tidg = blockIdx.x * blockDim.x + threadIdx.x;
  const int nth  = gridDim.x * blockDim.x;
  // stage 1: all k <= STILE entirely in LDS (direction from global index)
  for (int i = threadIdx.x; i < STILE; i += 256) t[i] = buf[base + i];
  __syncthreads();
  for (int k = 2; k <= STILE; k <<= 1) {
    for (int j = k >> 1; j > 0; j >>= 1) {
      for (int i = threadIdx.x; i < STILE; i += 256) {
        int p = i ^ j;
        if (p > i) {
          bool dir = (((base + i) & k) == 0);
          u64 a = t[i], c = t[p];
          if ((a > c) == dir) { t[i] = c; t[p] = a; }
        }
      }
      __syncthreads();
    }
  }
  for (int i = threadIdx.x; i < STILE; i += 256) buf[base + i] = t[i];
  __threadfence(); g.sync(); __threadfence();
  // stages k > STILE: global passes for j >= STILE, LDS finish for j < STILE
  for (int k = STILE << 1; k <= SORTN; k <<= 1) {
    for (int j = k >> 1; j >= STILE; j >>= 1) {
      for (int i = tidg; i < SORTN; i += nth) {
        int p = i ^ j;
        if (p > i) {
          bool dir = ((i & k) == 0);
          u64 a = buf[i], c = buf[p];
          if ((a > c) == dir) { buf[i] = c; buf[p] = a; }
        }
      }
      __threadfence(); g.sync(); __threadfence();
    }
    for (int i = threadIdx.x; i < STILE; i += 256) t[i] = buf[base + i];
    __syncthreads();
    bool dir = ((base & k) == 0);  // uniform per tile (k > STILE)
    for (int j = STILE >> 1; j > 0; j >>= 1) {
      for (int i = threadIdx.x; i < STILE; i += 256) {
        int p = i ^ j;
        if (p > i) {
          u64 a = t[i], c = t[p];
          if ((a > c) == dir) { t[i] = c; t[p] = a; }
        }
      }
      __syncthreads();
    }
    for (int i = threadIdx.x; i < STILE; i += 256) buf[base + i] = t[i];
    __threadfence(); g.sync(); __threadfence();
  }
}

// sorted position i == cluster id of chosen edge
__global__ __launch_bounds__(256)
void k_assign(const u64* __restrict__ buf, const int* __restrict__ src,
              const int* __restrict__ dst, const float* __restrict__ esc,
              int* cluster, int* memA, int* memB, float* scoreC,
              const u32* __restrict__ scalars) {
  int i = blockIdx.x * blockDim.x + threadIdx.x;
  if (i >= (int)scalars[0]) return;
  u64 k = buf[i];
  u32 e = (u32)(k & 0xffffffffull);
  int s = src[e], d = dst[e];
  cluster[s] = i; cluster[d] = i;
  scoreC[i] = esc[e];
  memA[i] = s;
  memB[i] = (s == d) ? -1 : d;   // self-loop: single member
}

// exclusive scan of unmatched nodes -> trailing singleton cluster ids
__global__ __launch_bounds__(256)
void k_scan1(const u8* __restrict__ matched, u32* partials, int N) {
  __shared__ u32 sh[256];
  int b = blockIdx.x, tx = threadIdx.x;
  int v0 = b * 1024 + tx * 4;
  u32 c = 0;
  #pragma unroll
  for (int q = 0; q < 4; q++) { int v = v0 + q; if (v < N && !matched[v]) c++; }
  sh[tx] = c; __syncthreads();
  for (int s = 128; s > 0; s >>= 1) { if (tx < s) sh[tx] += sh[tx + s]; __syncthreads(); }
  if (tx == 0) partials[b] = sh[0];
}

__global__ void k_scan2(const u32* partials, u32* partials2, u32* scalars, int NB) {
  if (blockIdx.x == 0 && threadIdx.x == 0) {
    u32 run = 0;
    for (int i = 0; i < NB; i++) { partials2[i] = run; run += partials[i]; }
    scalars[1] = run;                 // total unmatched
    scalars[2] = scalars[0] + run;    // num_clusters
  }
}

__global__ __launch_bounds__(256)
void k_scan3(const u8* __restrict__ matched, const u32* __restrict__ partials2,
             const u32* __restrict__ scalars, int* cluster, int* memA, int* memB, int N) {
  __shared__ u32 sh[256];
  int b = blockIdx.x, tx = threadIdx.x;
  int v0 = b * 1024 + tx * 4;
  u32 f[4]; u32 c = 0;
  #pragma unroll
  for (int q = 0; q < 4; q++) { int v = v0 + q; f[q] = (v < N && !matched[v]); c += f[q]; }
  sh[tx] = c; __syncthreads();
  for (int s = 1; s < 256; s <<= 1) {      // Hillis-Steele inclusive scan
    u32 x = sh[tx];
    u32 y = (tx >= s) ? sh[tx - s] : 0;
    __syncthreads();
    sh[tx] = x + y;
    __syncthreads();
  }
  u32 base = scalars[0] + partials2[b] + (sh[tx] - c);
  #pragma unroll
  for (int q = 0; q < 4; q++) {
    if (f[q]) {
      int v = v0 + q;
      int cc = (int)base++;
      cluster[v] = cc; memA[cc] = v; memB[cc] = -1;
    }
  }
}

// new_x: wave per output row; <=2 members per cluster; zero tail rows
__global__ __launch_bounds__(256)
void k_newx(const float4* __restrict__ x4, const int* __restrict__ memA,
            const int* __restrict__ memB, const float* __restrict__ scoreC,
            const u32* __restrict__ scalars, float4* __restrict__ out4, int N) {
  int gt = blockIdx.x * blockDim.x + threadIdx.x;
  int w = gt >> 6, lane = gt & 63;
  if (w >= N) return;
  int nc = (int)scalars[2];
  float4 o;
  if (w < nc) {
    int a = memA[w], b = memB[w];
    float s = scoreC[w];
    float4 va = x4[(size_t)a * 64 + lane];
    float ox = va.x, oy = va.y, oz = va.z, ow = va.w;
    if (b >= 0) {
      float4 vb = x4[(size_t)b * 64 + lane];
      ox += vb.x; oy += vb.y; oz += vb.z; ow += vb.w;
    }
    o = make_float4(ox * s, oy * s, oz * s, ow * s);
  } else {
    o = make_float4(0.f, 0.f, 0.f, 0.f);
  }
  out4[(size_t)w * 64 + lane] = o;
}

__global__ __launch_bounds__(256)
void k_remap(const int* __restrict__ ei, const int* __restrict__ cluster,
             float* __restrict__ outE, int twoE) {
  int i = blockIdx.x * blockDim.x + threadIdx.x;
  if (i < twoE) outE[i] = (float)cluster[ei[i]];
}

__global__ __launch_bounds__(256)
void k_tail(float* __restrict__ outB, const u32* __restrict__ scalars, int N) {
  int i = blockIdx.x * blockDim.x + threadIdx.x;
  if (i < N) outB[i] = 0.0f;                  // batch is all zeros
  if (i == 0) outB[N] = (float)scalars[2];    // num_clusters
}

extern "C" void kernel_launch(void* const* d_in, const int* in_sizes, int n_in,
                              void* d_out, int out_size, void* d_ws, size_t ws_size,
                              hipStream_t stream) {
  const float* x    = (const float*)d_in[0];
  const int*   ei   = (const int*)d_in[1];
  const float* W    = (const float*)d_in[3];
  const float* bvec = (const float*)d_in[4];
  int N = in_sizes[2];
  int E = in_sizes[1] / 2;

  // workspace carve-out (~34 MB)
  char* p = (char*)d_ws;
  auto alloc = [&](size_t bytes) { char* r = p; p += (bytes + 255) & ~(size_t)255; return r; };
  float*  s_src    = (float*)alloc((size_t)N * 4);
  float*  s_dst    = (float*)alloc((size_t)N * 4);
  u32*    m_ord    = (u32*)alloc((size_t)N * 4);
  double* ssum     = (double*)alloc((size_t)N * 8);
  float*  exb      = (float*)alloc((size_t)E * 4);
  float*  esc      = (float*)alloc((size_t)E * 4);
  u64*    key      = (u64*)alloc((size_t)E * 8);
  u8*     alive    = (u8*)alloc((size_t)E);
  u8*     matched  = (u8*)alloc((size_t)N);
  u64*    node_min = (u64*)alloc((size_t)2 * N * 8);
  u64*    sortbuf  = (u64*)alloc((size_t)SORTN * 8);
  int*    cluster  = (int*)alloc((size_t)N * 4);
  int*    memA     = (int*)alloc((size_t)N * 4);
  int*    memB     = (int*)alloc((size_t)N * 4);
  float*  scoreC   = (float*)alloc((size_t)N * 4);
  u32*    flags    = (u32*)alloc(1024);
  u32*    partials = (u32*)alloc(4096);
  u32*    partials2= (u32*)alloc(4096);
  u32*    scalars  = (u32*)alloc(256);
  (void)ws_size; (void)out_size; (void)n_in;

  const int* srcp = ei;
  const int* dstp = ei + E;
  float* out  = (float*)d_out;
  float* outX = out;
  float* outE = out + (size_t)N * 256;
  float* outB = outE + (size_t)2 * E;

  int cover = (N > SORTN) ? N : SORTN;
  k_init<<<(cover + 255) / 256, 256, 0, stream>>>(m_ord, ssum, matched, node_min,
                                                  scoreC, sortbuf, flags, scalars, N);
  k_dots<<<((size_t)N * 64 + 255) / 256, 256, 0, stream>>>(
      (const float4*)x, (const float4*)W, s_src, s_dst, N);
  k_max<<<(E + 255) / 256, 256, 0, stream>>>(srcp, dstp, s_src, s_dst, bvec, m_ord, E);
  k_expsum<<<(E + 255) / 256, 256, 0, stream>>>(srcp, dstp, s_src, s_dst, bvec, m_ord,
                                                exb, ssum, E);
  k_scorekey<<<(E + 255) / 256, 256, 0, stream>>>(dstp, exb, ssum, esc, key, alive, E);

  {
    void* args[] = { (void*)&srcp, (void*)&dstp, (void*)&key, (void*)&alive,
                     (void*)&matched, (void*)&node_min, (void*)&sortbuf,
                     (void*)&flags, (void*)&scalars, (void*)&N, (void*)&E };
    hipLaunchCooperativeKernel((const void*)k_match, dim3(MBLK), dim3(256), args, 0, stream);
  }
  {
    void* args[] = { (void*)&sortbuf };
    hipLaunchCooperativeKernel((const void*)k_sort, dim3(SORTN / STILE), dim3(256), args, 0, stream);
  }

  k_assign<<<SORTN / 256, 256, 0, stream>>>(sortbuf, srcp, dstp, esc,
                                            cluster, memA, memB, scoreC, scalars);
  int NB = (N + 1023) / 1024;
  k_scan1<<<NB, 256, 0, stream>>>(matched, partials, N);
  k_scan2<<<1, 64, 0, stream>>>(partials, partials2, scalars, NB);
  k_scan3<<<NB, 256, 0, stream>>>(matched, partials2, scalars, cluster, memA, memB, N);

  k_newx<<<((size_t)N * 64 + 255) / 256, 256, 0, stream>>>(
      (const float4*)x, memA, memB, scoreC, scalars, (float4*)outX, N);
  k_remap<<<(2 * E + 255) / 256, 256, 0, stream>>>(ei, cluster, outE, 2 * E);
  k_tail<<<(N + 255) / 256, 256, 0, stream>>>(outB, scalars, N);
}